// Round 6
// baseline (141.636 us; speedup 1.0000x reference)
//
#include <hip/hip_runtime.h>
#include <hip/hip_bf16.h>

typedef __hip_bfloat16 bf16;
typedef __attribute__((ext_vector_type(8))) short short8;   // bf16x8 MFMA frag (4 VGPR)
typedef __attribute__((ext_vector_type(4))) short short4v;  // bf16x4 (8 B)
typedef __attribute__((ext_vector_type(4))) float float4v;  // MFMA acc frag

// ---- geometry ----
#define HALO_H 18
#define HALO_W 10
#define CS 24          // xs channel stride: lane stride 48B -> 2-way banks, 16B aligned
#define KS 136         // hs k stride: row stride 272B, 16B aligned
#define XS_W 6         // wave-region width: 4 pixels + 2 halo columns
#define XS_REG (XS_W * HALO_H * CS)   // 2592 el per ngrp region
#define HS_EL (128 * KS)              // 17408 el per hs buffer

// ---- ws layout ----
// bf16:  W1E [128][160] (20480 el) + W2B [16][128] (2048 el)  = 45056 B
// float: b1e[128], b2[16] at byte 45056
// xT bf16 [b][h][w][c] at byte 65536, 16 MB
#define W2B_EL 20480
#define WSF_BYTE 45056
#define XT_BYTE 65536

__device__ __forceinline__ unsigned int bfbits(float f) {
    bf16 h = __float2bfloat16(f);
    unsigned short u;
    __builtin_memcpy(&u, &h, 2);
    return (unsigned int)u;
}

// One kernel: blocks [0, tb) transpose x -> xT bf16 [b][h][w][c];
// blocks [tb, tb+80) build fused weights.  (unchanged from round 5)
__global__ void prep_all(const float* __restrict__ x,
                         const float* __restrict__ Wx, const float* __restrict__ bx,
                         const float* __restrict__ Wy, const float* __restrict__ by,
                         const float* __restrict__ W1, const float* __restrict__ b1,
                         const float* __restrict__ W2, const float* __restrict__ b2,
                         bf16* __restrict__ wsb, float* __restrict__ wsf,
                         bf16* __restrict__ xT, int tb) {
    int blk = blockIdx.x;
    int tid = threadIdx.x;
    if (blk < tb) {
        int b = blk >> 7;
        int w = tid >> 1, half = tid & 1;
        const float* src = x + (((size_t)(b * 16 + half * 8)) * 128 + (blk & 127)) * 128 + w;
        unsigned int pk[4];
#pragma unroll
        for (int i = 0; i < 4; ++i) {
            unsigned int lo = bfbits(src[(size_t)(2 * i) * 16384]);
            unsigned int hi = bfbits(src[(size_t)(2 * i + 1) * 16384]);
            pk[i] = lo | (hi << 16);
        }
        *(uint4*)(xT + ((size_t)blk * 128 + w) * 16 + half * 8) =
            make_uint4(pk[0], pk[1], pk[2], pk[3]);
        return;
    }
    int t = (blk - tb) * 256 + tid;
    int stride = 80 * 256;
    for (int f = t; f < 128 * 160; f += stride) {
        int j = f / 160, k = f - j * 160;
        int g = k >> 4, c = k & 15;
        float v = 0.0f;
        if (g < 9) {
            for (int o = 0; o < 16; ++o) {
                float wx = Wx[(o * 16 + c) * 9 + g];
                float wy = Wy[(o * 16 + c) * 9 + g];
                v = fmaf(W1[j * 48 + o], wx, v);
                v = fmaf(W1[j * 48 + 16 + o], wy, v);
            }
            if (g == 4) v += W1[j * 48 + 32 + c];
        }
        wsb[f] = __float2bfloat16(v);
    }
    for (int f = t; f < 2048; f += stride) wsb[W2B_EL + f] = __float2bfloat16(W2[f]);
    for (int j = t; j < 128; j += stride) {
        float v = b1[j];
        for (int o = 0; o < 16; ++o) {
            v = fmaf(W1[j * 48 + o], bx[o], v);
            v = fmaf(W1[j * 48 + 16 + o], by[o], v);
        }
        wsf[j] = v;
    }
    if (t < 16) wsf[128 + t] = b2[t];
}

// ---------------- main kernel: ONE barrier per tile ----------------
// xs: per-ngrp region, redundantly written by both m-half waves (identical
// data, benign race) -> commit->GEMM1 needs no barrier (within-wave DS order).
// hs: double-buffered (parity per tile) -> kills the epilogue(t+1) vs
// GEMM2(t) WAR; single RAW barrier after epilogue remains.
__global__ __launch_bounds__(256, 2) void nca_mfma_t(const bf16* __restrict__ xT,
                                                     const bf16* __restrict__ wsb,
                                                     const float* __restrict__ wsf,
                                                     float* __restrict__ out,
                                                     int gridTiles) {
    __shared__ __align__(16) bf16 xs[2][XS_REG];   // [ngrp] regions
    __shared__ __align__(16) bf16 hs[2][HS_EL];    // tile-parity double buffer
    // LDS total = 10368 + 69632 = 80000 B -> exactly 2 blocks/CU

    const int tid = threadIdx.x;
    const int wave = tid >> 6;
    const int lane = tid & 63;
    const int hl = lane & 15;
    const int quad = lane >> 4;
    const int r0 = quad * 4;
    const int mgrp = wave >> 1;
    const int ngrp = wave & 1;

    // ---- one-time: A fragments (W1e), W2 frags, biases ----
    short8 afrag[4][5];
#pragma unroll
    for (int mt = 0; mt < 4; ++mt) {
        int m = mgrp * 64 + mt * 16 + hl;
#pragma unroll
        for (int q = 0; q < 5; ++q)
            afrag[mt][q] = *(const short8*)(wsb + m * 160 + q * 32 + quad * 8);
    }
    short8 w2frag[4];
#pragma unroll
    for (int r = 0; r < 4; ++r)
        w2frag[r] = *(const short8*)(wsb + W2B_EL + hl * 128 + r * 32 + quad * 8);
    float b1r[4][4];
#pragma unroll
    for (int mt = 0; mt < 4; ++mt)
#pragma unroll
        for (int r = 0; r < 4; ++r) b1r[mt][r] = wsf[mgrp * 64 + mt * 16 + r0 + r];
    float b2r[4];
#pragma unroll
    for (int r = 0; r < 4; ++r) b2r[r] = wsf[128 + r0 + r];

    // ---- staging slot constants: wave stages its ngrp 6x18 region ----
    // 216 uint4 units (6 cols x 18 rows x 2 c-halves); lane handles u=lane+64s.
    int sc_lds[4], sc_row[4], sc_col[4], sc_cf[4];
#pragma unroll
    for (int s = 0; s < 4; ++s) {
        int u = lane + 64 * s;
        int pos = u >> 1, cf = u & 1;
        int col = pos / HALO_H, row = pos - col * HALO_H;
        sc_lds[s] = ngrp * XS_REG + (col * HALO_H + row) * CS + cf * 8;
        sc_row[s] = row; sc_col[s] = col; sc_cf[s] = cf;
    }
    const bool has3 = (lane < 24);   // 216 = 3*64 + 24

    uint4 pre[4];
    bf16* xsf = (bf16*)xs;

#define LOAD_TILE(T)                                                                  \
    {                                                                                 \
        int b_ = (T) >> 7, rem_ = (T) & 127;                                          \
        int w0_ = (rem_ >> 3) * 8, h0_ = (rem_ & 7) * 16;                             \
        _Pragma("unroll")                                                             \
        for (int s = 0; s < 4; ++s) {                                                 \
            int gh = h0_ - 1 + sc_row[s];                                             \
            int gw = w0_ - 1 + ngrp * 4 + sc_col[s];                                  \
            bool ok = (s < 3 || has3) && ((unsigned)gh < 128u) && ((unsigned)gw < 128u); \
            long off = (((long)b_ << 14) + gh * 128 + gw) * 16 + (sc_cf[s] << 3);     \
            const uint4* p = (const uint4*)(xT + (ok ? off : 0));                     \
            uint4 v = *p;                                                             \
            if (!ok) { v.x = 0; v.y = 0; v.z = 0; v.w = 0; }                          \
            pre[s] = v;                                                               \
        }                                                                             \
    }

    int t = blockIdx.x;
    LOAD_TILE(t);
    int tb = 0;

    for (; t < 4096; t += gridTiles) {
        const int b = t >> 7;
        const int rem = t & 127;
        const int w0 = (rem >> 3) * 8;
        const int h0 = (rem & 7) * 16;

        // ---- commit prefetched region (own-wave duplicate write, no barrier) ----
#pragma unroll
        for (int s = 0; s < 3; ++s)
            *(uint4*)(xsf + sc_lds[s]) = pre[s];
        if (has3) *(uint4*)(xsf + sc_lds[3]) = pre[3];

        // ---- issue next tile's global prefetch (covers GEMM1 + epilogue) ----
        int tn = t + gridTiles;
        if (tn < 4096) LOAD_TILE(tn);

        // ---- GEMM1: acc = W1e @ patches (reads only cells this wave wrote) ----
        float4v acc[4][4];
#pragma unroll
        for (int mt = 0; mt < 4; ++mt)
#pragma unroll
            for (int nt = 0; nt < 4; ++nt) acc[mt][nt] = (float4v)0.0f;

        const bf16* xw = xsf + ngrp * XS_REG;
#pragma unroll
        for (int q = 0; q < 5; ++q) {
            int g = q * 2 + (quad >> 1);
            if (g > 8) g = 8;  // K-pad: A rows are zero there
            int kh = g / 3, kw = g - kh * 3;
            int c0 = (quad & 1) * 8;
            short8 bfrag[4];
#pragma unroll
            for (int nt = 0; nt < 4; ++nt)
                bfrag[nt] = *(const short8*)(xw + ((nt + kw) * HALO_H + hl + kh) * CS + c0);
#pragma unroll
            for (int nt = 0; nt < 4; ++nt)
#pragma unroll
                for (int mt = 0; mt < 4; ++mt)
                    acc[mt][nt] = __builtin_amdgcn_mfma_f32_16x16x32_bf16(
                        afrag[mt][q], bfrag[nt], acc[mt][nt], 0, 0, 0);
        }

        // ---- epilogue 1: bias + relu -> hs[tb][pixel][m] bf16 ----
        bf16* hsw = (bf16*)hs + tb * HS_EL;
#pragma unroll
        for (int mt = 0; mt < 4; ++mt)
#pragma unroll
            for (int nt = 0; nt < 4; ++nt) {
                int p = (ngrp * 4 + nt) * 16 + hl;
                int m = mgrp * 64 + mt * 16 + r0;
                short4v pk;
#pragma unroll
                for (int r = 0; r < 4; ++r) {
                    float v = acc[mt][nt][r] + b1r[mt][r];
                    v = fmaxf(v, 0.0f);
                    bf16 hb = __float2bfloat16(v);
                    pk[r] = *reinterpret_cast<short*>(&hb);
                }
                *(short4v*)(hsw + p * KS + m) = pk;
            }
        __syncthreads();  // the ONE barrier: hs[tb] complete

        // ---- GEMM2: out16 = W2 @ h ----
        float4v acc2[2];
        acc2[0] = (float4v)0.0f;
        acc2[1] = (float4v)0.0f;
#pragma unroll
        for (int r = 0; r < 4; ++r) {
#pragma unroll
            for (int i = 0; i < 2; ++i) {
                int p = (wave * 2 + i) * 16 + hl;
                short8 bfrag = *(const short8*)(hsw + p * KS + r * 32 + quad * 8);
                acc2[i] = __builtin_amdgcn_mfma_f32_16x16x32_bf16(
                    w2frag[r], bfrag, acc2[i], 0, 0, 0);
            }
        }

        // ---- store out[b][w0+nt][h0+hl][r0..r0+3] fp32, coalesced ----
#pragma unroll
        for (int i = 0; i < 2; ++i) {
            int nt = wave * 2 + i;
            size_t ofs = (((size_t)b * 128 + (w0 + nt)) * 128 + (h0 + hl)) * 16 + r0;
            float4 v = make_float4(acc2[i][0] + b2r[0], acc2[i][1] + b2r[1],
                                   acc2[i][2] + b2r[2], acc2[i][3] + b2r[3]);
            *(float4*)(out + ofs) = v;
        }
        tb ^= 1;
    }
#undef LOAD_TILE
}

// ---------------- fallback (round-3 proven kernel, fp32 x) ----------------
__global__ __launch_bounds__(256, 2) void nca_mfma_fb(const float* __restrict__ x,
                                                      const bf16* __restrict__ wsb,
                                                      const float* __restrict__ wsf,
                                                      float* __restrict__ out,
                                                      int gridTiles) {
    __shared__ bf16 xsb[HALO_W * HALO_H * CS];
    __shared__ bf16 hsb[128 * KS];

    const int tid = threadIdx.x;
    const int wave = tid >> 6;
    const int lane = tid & 63;
    const int hl = lane & 15;
    const int quad = lane >> 4;
    const int r0 = quad * 4;
    const int mgrp = wave >> 1;
    const int ngrp = wave & 1;

    short8 afrag[4][5];
#pragma unroll
    for (int mt = 0; mt < 4; ++mt) {
        int m = mgrp * 64 + mt * 16 + hl;
#pragma unroll
        for (int q = 0; q < 5; ++q)
            afrag[mt][q] = *(const short8*)(wsb + m * 160 + q * 32 + quad * 8);
    }
    short8 w2frag[4];
#pragma unroll
    for (int r = 0; r < 4; ++r)
        w2frag[r] = *(const short8*)(wsb + W2B_EL + hl * 128 + r * 32 + quad * 8);
    float b1r[4][4];
#pragma unroll
    for (int mt = 0; mt < 4; ++mt)
#pragma unroll
        for (int r = 0; r < 4; ++r) b1r[mt][r] = wsf[mgrp * 64 + mt * 16 + r0 + r];
    float b2r[4];
#pragma unroll
    for (int r = 0; r < 4; ++r) b2r[r] = wsf[128 + r0 + r];

    for (int t = blockIdx.x; t < 4096; t += gridTiles) {
        int b = t >> 7;
        int rem = t & 127;
        int wt = rem >> 3, ht = rem & 7;
        int h0 = ht * 16, w0 = wt * 8;

        __syncthreads();

        const float* xb = x + (size_t)b * 16 * 128 * 128;
        for (int f = tid; f < 16 * HALO_H * HALO_W; f += 256) {
            int c = f / (HALO_H * HALO_W);
            int rr = f - c * (HALO_H * HALO_W);
            int hh = rr / HALO_W;
            int ww = rr - hh * HALO_W;
            int gh = h0 - 1 + hh, gw = w0 - 1 + ww;
            float v = 0.0f;
            if ((unsigned)gh < 128u && (unsigned)gw < 128u)
                v = xb[(c * 128 + gh) * 128 + gw];
            xsb[(ww * HALO_H + hh) * CS + c] = __float2bfloat16(v);
        }
        __syncthreads();

        float4v acc[4][4];
#pragma unroll
        for (int mt = 0; mt < 4; ++mt)
#pragma unroll
            for (int nt = 0; nt < 4; ++nt) acc[mt][nt] = (float4v)0.0f;

#pragma unroll
        for (int q = 0; q < 5; ++q) {
            int g = q * 2 + (quad >> 1);
            if (g > 8) g = 8;
            int kh = g / 3, kw = g - kh * 3;
            int c0 = (quad & 1) * 8;
            short8 bfrag[4];
#pragma unroll
            for (int nt = 0; nt < 4; ++nt) {
                int ww = ngrp * 4 + nt + kw;
                bfrag[nt] = *(const short8*)(xsb + (ww * HALO_H + hl + kh) * CS + c0);
            }
#pragma unroll
            for (int nt = 0; nt < 4; ++nt)
#pragma unroll
                for (int mt = 0; mt < 4; ++mt)
                    acc[mt][nt] = __builtin_amdgcn_mfma_f32_16x16x32_bf16(
                        afrag[mt][q], bfrag[nt], acc[mt][nt], 0, 0, 0);
        }

#pragma unroll
        for (int mt = 0; mt < 4; ++mt)
#pragma unroll
            for (int nt = 0; nt < 4; ++nt) {
                int p = (ngrp * 4 + nt) * 16 + hl;
                int m = mgrp * 64 + mt * 16 + r0;
                short4v pk;
#pragma unroll
                for (int r = 0; r < 4; ++r) {
                    float v = acc[mt][nt][r] + b1r[mt][r];
                    v = fmaxf(v, 0.0f);
                    bf16 hb = __float2bfloat16(v);
                    pk[r] = *reinterpret_cast<short*>(&hb);
                }
                *(short4v*)(hsb + p * KS + m) = pk;
            }
        __syncthreads();

        float4v acc2[2];
        acc2[0] = (float4v)0.0f;
        acc2[1] = (float4v)0.0f;
#pragma unroll
        for (int r = 0; r < 4; ++r) {
#pragma unroll
            for (int i = 0; i < 2; ++i) {
                int p = (wave * 2 + i) * 16 + hl;
                short8 bfrag = *(const short8*)(hsb + p * KS + r * 32 + quad * 8);
                acc2[i] = __builtin_amdgcn_mfma_f32_16x16x32_bf16(
                    w2frag[r], bfrag, acc2[i], 0, 0, 0);
            }
        }

#pragma unroll
        for (int i = 0; i < 2; ++i) {
            int nt = wave * 2 + i;
            size_t ofs = (((size_t)b * 128 + (w0 + nt)) * 128 + (h0 + hl)) * 16 + r0;
            float4 v = make_float4(acc2[i][0] + b2r[0], acc2[i][1] + b2r[1],
                                   acc2[i][2] + b2r[2], acc2[i][3] + b2r[3]);
            *(float4*)(out + ofs) = v;
        }
    }
}

extern "C" void kernel_launch(void* const* d_in, const int* in_sizes, int n_in,
                              void* d_out, int out_size, void* d_ws, size_t ws_size,
                              hipStream_t stream) {
    const float* x  = (const float*)d_in[0];
    const float* Wx = (const float*)d_in[1];
    const float* bx = (const float*)d_in[2];
    const float* Wy = (const float*)d_in[3];
    const float* by = (const float*)d_in[4];
    const float* W1 = (const float*)d_in[5];
    const float* b1 = (const float*)d_in[6];
    const float* W2 = (const float*)d_in[7];
    const float* b2 = (const float*)d_in[8];
    bf16* wsb = (bf16*)d_ws;
    float* wsf = (float*)((char*)d_ws + WSF_BYTE);
    bf16* xT = (bf16*)((char*)d_ws + XT_BYTE);
    float* out = (float*)d_out;

    const size_t need = (size_t)XT_BYTE + (size_t)32 * 128 * 128 * 16 * 2;  // 16.8 MB
    const bool big = ws_size >= need;
    const int tb = big ? 4096 : 0;

    hipLaunchKernelGGL(prep_all, dim3(tb + 80), dim3(256), 0, stream,
                       x, Wx, bx, Wy, by, W1, b1, W2, b2, wsb, wsf, xT, tb);
    if (big) {
        const int grid = 512;  // exactly 2 blocks/CU, 8 tiles/block, zero tail
        hipLaunchKernelGGL(nca_mfma_t, dim3(grid), dim3(256), 0, stream,
                           xT, wsb, wsf, out, grid);
    } else {
        const int grid = 1024;
        hipLaunchKernelGGL(nca_mfma_fb, dim3(grid), dim3(256), 0, stream,
                           x, wsb, wsf, out, grid);
    }
}

// Round 7
// 125.556 us; speedup vs baseline: 1.1281x; 1.1281x over previous
//
#include <hip/hip_runtime.h>
#include <hip/hip_bf16.h>

typedef __hip_bfloat16 bf16;
typedef __attribute__((ext_vector_type(8))) short short8;   // bf16x8 MFMA frag (4 VGPR)
typedef __attribute__((ext_vector_type(4))) short short4v;  // bf16x4 (8 B)
typedef __attribute__((ext_vector_type(4))) float float4v;  // MFMA acc frag

// ---- geometry (main kernel): 16h x 4w = 64-px tiles ----
#define HALO_H 18
#define HALO_W4 6      // 4 pixels + 2 halo columns
#define CS 24          // xs channel stride: lane stride 48B -> 2-way banks, 16B aligned
#define KS 136         // hs k stride: row stride 272B = 17*16 -> 16B aligned, 2-way banks
#define XS_EL (HALO_W4 * HALO_H * CS)   // 2592 el per buffer

// ---- ws layout ----
// bf16:  W1E [128][160] (20480 el) + W2B [16][128] (2048 el)  = 45056 B
// float: b1e[128], b2[16] at byte 45056
// xT bf16 [b][h][w][c] at byte 65536, 16 MB
#define W2B_EL 20480
#define WSF_BYTE 45056
#define XT_BYTE 65536

// fallback geometry (round-3/5 proven): 16h x 8w tiles
#define HALO_W 10

__device__ __forceinline__ unsigned int bfbits(float f) {
    bf16 h = __float2bfloat16(f);
    unsigned short u;
    __builtin_memcpy(&u, &h, 2);
    return (unsigned int)u;
}

// One kernel: blocks [0, tb) transpose x -> xT bf16 [b][h][w][c];
// blocks [tb, tb+80) build fused weights.  (unchanged from round 5)
__global__ void prep_all(const float* __restrict__ x,
                         const float* __restrict__ Wx, const float* __restrict__ bx,
                         const float* __restrict__ Wy, const float* __restrict__ by,
                         const float* __restrict__ W1, const float* __restrict__ b1,
                         const float* __restrict__ W2, const float* __restrict__ b2,
                         bf16* __restrict__ wsb, float* __restrict__ wsf,
                         bf16* __restrict__ xT, int tb) {
    int blk = blockIdx.x;
    int tid = threadIdx.x;
    if (blk < tb) {
        int b = blk >> 7;
        int w = tid >> 1, half = tid & 1;
        const float* src = x + (((size_t)(b * 16 + half * 8)) * 128 + (blk & 127)) * 128 + w;
        unsigned int pk[4];
#pragma unroll
        for (int i = 0; i < 4; ++i) {
            unsigned int lo = bfbits(src[(size_t)(2 * i) * 16384]);
            unsigned int hi = bfbits(src[(size_t)(2 * i + 1) * 16384]);
            pk[i] = lo | (hi << 16);
        }
        *(uint4*)(xT + ((size_t)blk * 128 + w) * 16 + half * 8) =
            make_uint4(pk[0], pk[1], pk[2], pk[3]);
        return;
    }
    int t = (blk - tb) * 256 + tid;
    int stride = 80 * 256;
    for (int f = t; f < 128 * 160; f += stride) {
        int j = f / 160, k = f - j * 160;
        int g = k >> 4, c = k & 15;
        float v = 0.0f;
        if (g < 9) {
            for (int o = 0; o < 16; ++o) {
                float wx = Wx[(o * 16 + c) * 9 + g];
                float wy = Wy[(o * 16 + c) * 9 + g];
                v = fmaf(W1[j * 48 + o], wx, v);
                v = fmaf(W1[j * 48 + 16 + o], wy, v);
            }
            if (g == 4) v += W1[j * 48 + 32 + c];
        }
        wsb[f] = __float2bfloat16(v);
    }
    for (int f = t; f < 2048; f += stride) wsb[W2B_EL + f] = __float2bfloat16(W2[f]);
    for (int j = t; j < 128; j += stride) {
        float v = b1[j];
        for (int o = 0; o < 16; ++o) {
            v = fmaf(W1[j * 48 + o], bx[o], v);
            v = fmaf(W1[j * 48 + 16 + o], by[o], v);
        }
        wsf[j] = v;
    }
    if (t < 16) wsf[128 + t] = b2[t];
}

// ---------------- main kernel: 64-px tiles, wave = m-quarter x full n ----------------
// Register diet vs round 5: afrag 80->40, acc 64->32, b1r 16->8, pre 8->4.
// LDS 27.8 KB. __launch_bounds__(256,3): cap 170 VGPR (estimate ~150, safe
// margin — round-4 spill disaster was ~200 crammed into 128).
__global__ __launch_bounds__(256, 3) void nca_mfma_t4(const bf16* __restrict__ xT,
                                                      const bf16* __restrict__ wsb,
                                                      const float* __restrict__ wsf,
                                                      float* __restrict__ out,
                                                      int gridTiles) {
    __shared__ __align__(16) bf16 xs[2][XS_EL];   // double-buffered x tile
    __shared__ __align__(16) bf16 hs[64 * KS];    // hidden acts, [pixel][m]

    const int tid = threadIdx.x;
    const int wave = tid >> 6;      // m-quarter: m in [32*wave, 32*wave+32)
    const int lane = tid & 63;
    const int hl = lane & 15;
    const int quad = lane >> 4;
    const int r0 = quad * 4;

    // ---- one-time: A fragments (W1e rows of this wave's m-quarter) ----
    short8 afrag[2][5];
#pragma unroll
    for (int mt = 0; mt < 2; ++mt) {
        int m = wave * 32 + mt * 16 + hl;
#pragma unroll
        for (int q = 0; q < 5; ++q)
            afrag[mt][q] = *(const short8*)(wsb + m * 160 + q * 32 + quad * 8);
    }
    short8 w2frag[4];
#pragma unroll
    for (int r = 0; r < 4; ++r)
        w2frag[r] = *(const short8*)(wsb + W2B_EL + hl * 128 + r * 32 + quad * 8);
    float b1r[2][4];
#pragma unroll
    for (int mt = 0; mt < 2; ++mt)
#pragma unroll
        for (int r = 0; r < 4; ++r) b1r[mt][r] = wsf[wave * 32 + mt * 16 + r0 + r];
    float b2r[4];
#pragma unroll
    for (int r = 0; r < 4; ++r) b2r[r] = wsf[128 + r0 + r];

    // ---- staging decode: 216 uint4 units (6 cols x 18 rows x 2 c-halves) ----
    const bool hasu = (tid < 216);
    const int pos = tid >> 1, scf = tid & 1;
    const int scol = pos / HALO_H, srow = pos - scol * HALO_H;
    const int slds = (scol * HALO_H + srow) * CS + scf * 8;

    uint4 pre;

#define LOAD_TILE(T)                                                                  \
    {                                                                                 \
        int b_ = (T) >> 8, rem_ = (T) & 255;                                          \
        int w0_ = (rem_ >> 3) * 4, h0_ = (rem_ & 7) * 16;                             \
        int gh = h0_ - 1 + srow, gw = w0_ - 1 + scol;                                 \
        bool ok = hasu && ((unsigned)gh < 128u) && ((unsigned)gw < 128u);             \
        long off = (((long)b_ << 14) + gh * 128 + gw) * 16 + (scf << 3);              \
        const uint4* p = (const uint4*)(xT + (ok ? off : 0));                         \
        uint4 v = *p;                                                                 \
        if (!ok) { v.x = 0; v.y = 0; v.z = 0; v.w = 0; }                              \
        pre = v;                                                                      \
    }

    int t = blockIdx.x;
    LOAD_TILE(t);
    int buf = 0;

    for (; t < 8192; t += gridTiles) {
        const int b = t >> 8;
        const int rem = t & 255;
        const int w0 = (rem >> 3) * 4;
        const int h0 = (rem & 7) * 16;

        // ---- commit prefetched tile -> xs[buf] ----
        if (hasu) *(uint4*)(&xs[buf][slds]) = pre;
        __syncthreads();  // xs[buf] ready (also orders prev GEMM2 reads vs epi)

        // ---- prefetch next tile (flies during GEMM1/epilogue) ----
        int tn = t + gridTiles;
        if (tn < 8192) LOAD_TILE(tn);

        // ---- GEMM1: acc[mt][nt] = W1e(quarter) @ patches(all 4 w-cols) ----
        float4v acc[2][4];
#pragma unroll
        for (int mt = 0; mt < 2; ++mt)
#pragma unroll
            for (int nt = 0; nt < 4; ++nt) acc[mt][nt] = (float4v)0.0f;

#pragma unroll
        for (int q = 0; q < 5; ++q) {
            int g = q * 2 + (quad >> 1);
            if (g > 8) g = 8;  // K-pad: A rows are zero there
            int kh = g / 3, kw = g - kh * 3;
            int c0 = (quad & 1) * 8;
            short8 bfrag[4];
#pragma unroll
            for (int nt = 0; nt < 4; ++nt)
                bfrag[nt] = *(const short8*)(&xs[buf][((nt + kw) * HALO_H + hl + kh) * CS + c0]);
#pragma unroll
            for (int nt = 0; nt < 4; ++nt)
#pragma unroll
                for (int mt = 0; mt < 2; ++mt)
                    acc[mt][nt] = __builtin_amdgcn_mfma_f32_16x16x32_bf16(
                        afrag[mt][q], bfrag[nt], acc[mt][nt], 0, 0, 0);
        }

        // ---- epilogue 1: bias + relu -> hs[pixel][m] bf16 ----
#pragma unroll
        for (int mt = 0; mt < 2; ++mt)
#pragma unroll
            for (int nt = 0; nt < 4; ++nt) {
                int p = nt * 16 + hl;
                int m = wave * 32 + mt * 16 + r0;
                short4v pk;
#pragma unroll
                for (int r = 0; r < 4; ++r) {
                    float v = acc[mt][nt][r] + b1r[mt][r];
                    v = fmaxf(v, 0.0f);
                    bf16 hb = __float2bfloat16(v);
                    pk[r] = *reinterpret_cast<short*>(&hb);
                }
                *(short4v*)(hs + p * KS + m) = pk;
            }
        __syncthreads();  // hs complete (cross-wave m-ranges)

        // ---- GEMM2: wave handles pixel-tile = its w-col ----
        float4v acc2 = (float4v)0.0f;
#pragma unroll
        for (int r = 0; r < 4; ++r) {
            short8 bfrag = *(const short8*)(hs + (wave * 16 + hl) * KS + r * 32 + quad * 8);
            acc2 = __builtin_amdgcn_mfma_f32_16x16x32_bf16(w2frag[r], bfrag, acc2, 0, 0, 0);
        }

        // ---- store out[b][w0+wave][h0+hl][r0..r0+3] fp32, coalesced ----
        size_t ofs = (((size_t)b * 128 + (w0 + wave)) * 128 + (h0 + hl)) * 16 + r0;
        *(float4*)(out + ofs) = make_float4(acc2[0] + b2r[0], acc2[1] + b2r[1],
                                            acc2[2] + b2r[2], acc2[3] + b2r[3]);
        buf ^= 1;
    }
#undef LOAD_TILE
}

// ---------------- fallback (round-3 proven kernel, fp32 x, 128-px tiles) ----------------
__global__ __launch_bounds__(256, 2) void nca_mfma_fb(const float* __restrict__ x,
                                                      const bf16* __restrict__ wsb,
                                                      const float* __restrict__ wsf,
                                                      float* __restrict__ out,
                                                      int gridTiles) {
    __shared__ bf16 xsb[HALO_W * HALO_H * CS];
    __shared__ bf16 hsb[128 * KS];

    const int tid = threadIdx.x;
    const int wave = tid >> 6;
    const int lane = tid & 63;
    const int hl = lane & 15;
    const int quad = lane >> 4;
    const int r0 = quad * 4;
    const int mgrp = wave >> 1;
    const int ngrp = wave & 1;

    short8 afrag[4][5];
#pragma unroll
    for (int mt = 0; mt < 4; ++mt) {
        int m = mgrp * 64 + mt * 16 + hl;
#pragma unroll
        for (int q = 0; q < 5; ++q)
            afrag[mt][q] = *(const short8*)(wsb + m * 160 + q * 32 + quad * 8);
    }
    short8 w2frag[4];
#pragma unroll
    for (int r = 0; r < 4; ++r)
        w2frag[r] = *(const short8*)(wsb + W2B_EL + hl * 128 + r * 32 + quad * 8);
    float b1r[4][4];
#pragma unroll
    for (int mt = 0; mt < 4; ++mt)
#pragma unroll
        for (int r = 0; r < 4; ++r) b1r[mt][r] = wsf[mgrp * 64 + mt * 16 + r0 + r];
    float b2r[4];
#pragma unroll
    for (int r = 0; r < 4; ++r) b2r[r] = wsf[128 + r0 + r];

    for (int t = blockIdx.x; t < 4096; t += gridTiles) {
        int b = t >> 7;
        int rem = t & 127;
        int wt = rem >> 3, ht = rem & 7;
        int h0 = ht * 16, w0 = wt * 8;

        __syncthreads();

        const float* xb = x + (size_t)b * 16 * 128 * 128;
        for (int f = tid; f < 16 * HALO_H * HALO_W; f += 256) {
            int c = f / (HALO_H * HALO_W);
            int rr = f - c * (HALO_H * HALO_W);
            int hh = rr / HALO_W;
            int ww = rr - hh * HALO_W;
            int gh = h0 - 1 + hh, gw = w0 - 1 + ww;
            float v = 0.0f;
            if ((unsigned)gh < 128u && (unsigned)gw < 128u)
                v = xb[(c * 128 + gh) * 128 + gw];
            xsb[(ww * HALO_H + hh) * CS + c] = __float2bfloat16(v);
        }
        __syncthreads();

        float4v acc[4][4];
#pragma unroll
        for (int mt = 0; mt < 4; ++mt)
#pragma unroll
            for (int nt = 0; nt < 4; ++nt) acc[mt][nt] = (float4v)0.0f;

#pragma unroll
        for (int q = 0; q < 5; ++q) {
            int g = q * 2 + (quad >> 1);
            if (g > 8) g = 8;
            int kh = g / 3, kw = g - kh * 3;
            int c0 = (quad & 1) * 8;
            short8 bfrag[4];
#pragma unroll
            for (int nt = 0; nt < 4; ++nt) {
                int ww = ngrp * 4 + nt + kw;
                bfrag[nt] = *(const short8*)(xsb + (ww * HALO_H + hl + kh) * CS + c0);
            }
#pragma unroll
            for (int nt = 0; nt < 4; ++nt)
#pragma unroll
                for (int mt = 0; mt < 4; ++mt)
                    acc[mt][nt] = __builtin_amdgcn_mfma_f32_16x16x32_bf16(
                        afrag[mt][q], bfrag[nt], acc[mt][nt], 0, 0, 0);
        }

#pragma unroll
        for (int mt = 0; mt < 4; ++mt)
#pragma unroll
            for (int nt = 0; nt < 4; ++nt) {
                int p = (ngrp * 4 + nt) * 16 + hl;
                int m = mgrp * 64 + mt * 16 + r0;
                short4v pk;
#pragma unroll
                for (int r = 0; r < 4; ++r) {
                    float v = acc[mt][nt][r] + b1r[mt][r];
                    v = fmaxf(v, 0.0f);
                    bf16 hb = __float2bfloat16(v);
                    pk[r] = *reinterpret_cast<short*>(&hb);
                }
                *(short4v*)(hsb + p * KS + m) = pk;
            }
        __syncthreads();

        float4v acc2[2];
        acc2[0] = (float4v)0.0f;
        acc2[1] = (float4v)0.0f;
#pragma unroll
        for (int r = 0; r < 4; ++r) {
#pragma unroll
            for (int i = 0; i < 2; ++i) {
                int p = (wave * 2 + i) * 16 + hl;
                short8 bfrag = *(const short8*)(hsb + p * KS + r * 32 + quad * 8);
                acc2[i] = __builtin_amdgcn_mfma_f32_16x16x32_bf16(
                    w2frag[r], bfrag, acc2[i], 0, 0, 0);
            }
        }

#pragma unroll
        for (int i = 0; i < 2; ++i) {
            int nt = wave * 2 + i;
            size_t ofs = (((size_t)b * 128 + (w0 + nt)) * 128 + (h0 + hl)) * 16 + r0;
            float4 v = make_float4(acc2[i][0] + b2r[0], acc2[i][1] + b2r[1],
                                   acc2[i][2] + b2r[2], acc2[i][3] + b2r[3]);
            *(float4*)(out + ofs) = v;
        }
    }
}

extern "C" void kernel_launch(void* const* d_in, const int* in_sizes, int n_in,
                              void* d_out, int out_size, void* d_ws, size_t ws_size,
                              hipStream_t stream) {
    const float* x  = (const float*)d_in[0];
    const float* Wx = (const float*)d_in[1];
    const float* bx = (const float*)d_in[2];
    const float* Wy = (const float*)d_in[3];
    const float* by = (const float*)d_in[4];
    const float* W1 = (const float*)d_in[5];
    const float* b1 = (const float*)d_in[6];
    const float* W2 = (const float*)d_in[7];
    const float* b2 = (const float*)d_in[8];
    bf16* wsb = (bf16*)d_ws;
    float* wsf = (float*)((char*)d_ws + WSF_BYTE);
    bf16* xT = (bf16*)((char*)d_ws + XT_BYTE);
    float* out = (float*)d_out;

    const size_t need = (size_t)XT_BYTE + (size_t)32 * 128 * 128 * 16 * 2;  // 16.8 MB
    const bool big = ws_size >= need;
    const int tb = big ? 4096 : 0;

    hipLaunchKernelGGL(prep_all, dim3(tb + 80), dim3(256), 0, stream,
                       x, Wx, bx, Wy, by, W1, b1, W2, b2, wsb, wsf, xT, tb);
    if (big) {
        const int grid = 1024;  // 8 tiles/block over 8192 tiles, zero tail
        hipLaunchKernelGGL(nca_mfma_t4, dim3(grid), dim3(256), 0, stream,
                           xT, wsb, wsf, out, grid);
    } else {
        const int grid = 1024;
        hipLaunchKernelGGL(nca_mfma_fb, dim3(grid), dim3(256), 0, stream,
                           x, wsb, wsf, out, grid);
    }
}

// Round 8
// 122.518 us; speedup vs baseline: 1.1560x; 1.0248x over previous
//
#include <hip/hip_runtime.h>
#include <hip/hip_bf16.h>

typedef __hip_bfloat16 bf16;
typedef __attribute__((ext_vector_type(8))) short short8;    // bf16x8 MFMA frag (4 VGPR)
typedef __attribute__((ext_vector_type(4))) short short4v;   // bf16x4 (8 B)
typedef __attribute__((ext_vector_type(4))) float float4v;   // 16x16 acc frag
typedef __attribute__((ext_vector_type(16))) float float16v; // 32x32 acc frag

// ---- geometry: 16h x 8w = 128-px tiles ----
#define HALO_H 18
#define HALO_W 10
#define CS 24          // xs channel stride: row stride 48B, 16B aligned
#define KS 136         // hs k stride: row stride 272B = 17*16B aligned
#define XS_EL (HALO_W * HALO_H * CS)   // 4320

// ---- ws layout ----
// bf16:  W1E [128][160] (20480 el) + W2B [16][128] (2048 el)  = 45056 B
// float: b1e[128], b2[16] at byte 45056
// xT bf16 [b][h][w][c] at byte 65536, 16 MB
#define W2B_EL 20480
#define WSF_BYTE 45056
#define XT_BYTE 65536

__device__ __forceinline__ unsigned int bfbits(float f) {
    bf16 h = __float2bfloat16(f);
    unsigned short u;
    __builtin_memcpy(&u, &h, 2);
    return (unsigned int)u;
}

// blocks [0, tb): transpose x -> xT bf16 [b][h][w][c]; blocks [tb, tb+80): weights.
__global__ void prep_all(const float* __restrict__ x,
                         const float* __restrict__ Wx, const float* __restrict__ bx,
                         const float* __restrict__ Wy, const float* __restrict__ by,
                         const float* __restrict__ W1, const float* __restrict__ b1,
                         const float* __restrict__ W2, const float* __restrict__ b2,
                         bf16* __restrict__ wsb, float* __restrict__ wsf,
                         bf16* __restrict__ xT, int tb) {
    int blk = blockIdx.x;
    int tid = threadIdx.x;
    if (blk < tb) {
        int b = blk >> 7;
        int w = tid >> 1, half = tid & 1;
        const float* src = x + (((size_t)(b * 16 + half * 8)) * 128 + (blk & 127)) * 128 + w;
        unsigned int pk[4];
#pragma unroll
        for (int i = 0; i < 4; ++i) {
            unsigned int lo = bfbits(src[(size_t)(2 * i) * 16384]);
            unsigned int hi = bfbits(src[(size_t)(2 * i + 1) * 16384]);
            pk[i] = lo | (hi << 16);
        }
        *(uint4*)(xT + ((size_t)blk * 128 + w) * 16 + half * 8) =
            make_uint4(pk[0], pk[1], pk[2], pk[3]);
        return;
    }
    int t = (blk - tb) * 256 + tid;
    int stride = 80 * 256;
    for (int f = t; f < 128 * 160; f += stride) {
        int j = f / 160, k = f - j * 160;
        int g = k >> 4, c = k & 15;
        float v = 0.0f;
        if (g < 9) {
            for (int o = 0; o < 16; ++o) {
                float wx = Wx[(o * 16 + c) * 9 + g];
                float wy = Wy[(o * 16 + c) * 9 + g];
                v = fmaf(W1[j * 48 + o], wx, v);
                v = fmaf(W1[j * 48 + 16 + o], wy, v);
            }
            if (g == 4) v += W1[j * 48 + 32 + c];
        }
        wsb[f] = __float2bfloat16(v);
    }
    for (int f = t; f < 2048; f += stride) wsb[W2B_EL + f] = __float2bfloat16(W2[f]);
    for (int j = t; j < 128; j += stride) {
        float v = b1[j];
        for (int o = 0; o < 16; ++o) {
            v = fmaf(W1[j * 48 + o], bx[o], v);
            v = fmaf(W1[j * 48 + 16 + o], by[o], v);
        }
        wsf[j] = v;
    }
    if (t < 16) wsf[128 + t] = b2[t];
}

// ---------------- main: GEMM1 on 32x32x16 MFMA (2x fewer frag bytes/MAC) ----------------
// Wave (of 4) = (mg = wave>>1) m-half x (ng = wave&1) n-half.
// Per wave: 2 m-tiles(32 rows) x 2 n-tiles(32 px), K = 9 taps x 16ch (no pad).
// DS per tile: 72 b128 rd (GEMM1) + 64 b64 wr (epi) + 64 b128 rd (GEMM2) + staging.
__global__ __launch_bounds__(256, 2) void nca_mfma_w(const bf16* __restrict__ xT,
                                                     const bf16* __restrict__ wsb,
                                                     const float* __restrict__ wsf,
                                                     float* __restrict__ out,
                                                     int gridTiles) {
    __shared__ __align__(16) bf16 xs[2][XS_EL];   // double-buffered x tile
    __shared__ __align__(16) bf16 hs[128 * KS];   // hidden acts [pixel][m]

    const int tid = threadIdx.x;
    const int wave = tid >> 6;
    const int lane = tid & 63;
    const int mg = wave >> 1;       // m-half: rows mg*64 .. +64
    const int ng = wave & 1;        // n-half: px ng*64 .. +64
    const int n32 = lane & 31;      // 32x32 operand index (m for A, px for B/D)
    const int hi = lane >> 5;       // k-half within K=16
    const int hh32 = n32 & 15;      // pixel local h
    const int wl32 = n32 >> 4;      // pixel w LSB
    // GEMM2 (16x16x32) lane decode
    const int hl = lane & 15;
    const int quad = lane >> 4;
    const int r0 = quad * 4;

    // ---- one-time: A fragments W1e[m][tap g] ----
    short8 afrag[2][9];
#pragma unroll
    for (int mt = 0; mt < 2; ++mt) {
        int m = mg * 64 + mt * 32 + n32;
#pragma unroll
        for (int g = 0; g < 9; ++g)
            afrag[mt][g] = *(const short8*)(wsb + m * 160 + g * 16 + hi * 8);
    }
    short8 w2frag[4];
#pragma unroll
    for (int r = 0; r < 4; ++r)
        w2frag[r] = *(const short8*)(wsb + W2B_EL + hl * 128 + r * 32 + quad * 8);
    // b1 in 32x32 C/D layout: row(reg) = (reg&3) + 8*(reg>>2) + 4*hi
    float b1r[2][16];
#pragma unroll
    for (int mt = 0; mt < 2; ++mt)
#pragma unroll
        for (int reg = 0; reg < 16; ++reg)
            b1r[mt][reg] = wsf[mg * 64 + mt * 32 + (reg & 3) + 8 * (reg >> 2) + 4 * hi];
    float b2r[4];
#pragma unroll
    for (int r = 0; r < 4; ++r) b2r[r] = wsf[128 + r0 + r];

    // ---- staging decode (r5-proven): 360 uint4 units ----
    const int hh0 = tid / 20, rr0 = tid % 20;
    const int sww0 = rr0 >> 1, shf0 = rr0 & 1;
    const int f1 = tid + 256;
    const int hh1 = f1 / 20, rr1 = f1 % 20;
    const int sww1 = rr1 >> 1, shf1 = rr1 & 1;
    const bool has1 = (tid < 104);

    uint4 pre0, pre1;

#define LOAD_TILE(T)                                                                  \
    {                                                                                 \
        int b_ = (T) >> 7, rem_ = (T) & 127;                                          \
        int w0_ = (rem_ >> 3) * 8, h0_ = (rem_ & 7) * 16;                             \
        {                                                                             \
            int gh = h0_ - 1 + hh0, gw = w0_ - 1 + sww0;                              \
            bool ok = ((unsigned)gh < 128u) && ((unsigned)gw < 128u);                 \
            long off = (((long)b_ << 14) + gh * 128 + gw) * 16 + (shf0 << 3);         \
            const uint4* p = (const uint4*)(xT + (ok ? off : 0));                     \
            uint4 v = *p;                                                             \
            if (!ok) { v.x = 0; v.y = 0; v.z = 0; v.w = 0; }                          \
            pre0 = v;                                                                 \
        }                                                                             \
        if (has1) {                                                                   \
            int gh = h0_ - 1 + hh1, gw = w0_ - 1 + sww1;                              \
            bool ok = ((unsigned)gh < 128u) && ((unsigned)gw < 128u);                 \
            long off = (((long)b_ << 14) + gh * 128 + gw) * 16 + (shf1 << 3);         \
            const uint4* p = (const uint4*)(xT + (ok ? off : 0));                     \
            uint4 v = *p;                                                             \
            if (!ok) { v.x = 0; v.y = 0; v.z = 0; v.w = 0; }                          \
            pre1 = v;                                                                 \
        }                                                                             \
    }

    int t = blockIdx.x;
    LOAD_TILE(t);
    int buf = 0;

    for (; t < 4096; t += gridTiles) {
        const int b = t >> 7;
        const int rem = t & 127;
        const int w0 = (rem >> 3) * 8;
        const int h0 = (rem & 7) * 16;

        // ---- commit prefetched tile -> xs[buf] ----
        *(uint4*)(&xs[buf][(sww0 * HALO_H + hh0) * CS + shf0 * 8]) = pre0;
        if (has1) *(uint4*)(&xs[buf][(sww1 * HALO_H + hh1) * CS + shf1 * 8]) = pre1;
        __syncthreads();  // xs[buf] ready; prev iter's hs reads done

        // ---- prefetch next tile (flies during GEMM1/epilogue) ----
        int tn = t + gridTiles;
        if (tn < 4096) LOAD_TILE(tn);

        // ---- GEMM1: acc = W1e @ patches + b1 (bias pre-loaded as C) ----
        float16v acc[2][2];
#pragma unroll
        for (int mt = 0; mt < 2; ++mt)
#pragma unroll
            for (int nt = 0; nt < 2; ++nt)
#pragma unroll
                for (int reg = 0; reg < 16; ++reg)
                    acc[mt][nt][reg] = b1r[mt][reg];

#pragma unroll
        for (int g = 0; g < 9; ++g) {
            const int kh = g / 3, kw = g - kh * 3;
            short8 bfrag[2];
#pragma unroll
            for (int nt = 0; nt < 2; ++nt) {
                int w = (ng * 2 + nt) * 2 + wl32;
                bfrag[nt] = *(const short8*)(&xs[buf][((w + kw) * HALO_H + hh32 + kh) * CS + hi * 8]);
            }
#pragma unroll
            for (int nt = 0; nt < 2; ++nt)
#pragma unroll
                for (int mt = 0; mt < 2; ++mt)
                    acc[mt][nt] = __builtin_amdgcn_mfma_f32_32x32x16_bf16(
                        afrag[mt][g], bfrag[nt], acc[mt][nt], 0, 0, 0);
        }

        // ---- epilogue 1: relu -> hs[pixel][m] bf16 ----
#pragma unroll
        for (int mt = 0; mt < 2; ++mt)
#pragma unroll
            for (int nt = 0; nt < 2; ++nt) {
                int p = (ng * 2 + nt) * 32 + n32;
#pragma unroll
                for (int rg = 0; rg < 4; ++rg) {
                    int m0 = mg * 64 + mt * 32 + rg * 8 + 4 * hi;
                    short4v pk;
#pragma unroll
                    for (int r = 0; r < 4; ++r) {
                        float v = fmaxf(acc[mt][nt][rg * 4 + r], 0.0f);
                        bf16 hb = __float2bfloat16(v);
                        pk[r] = *reinterpret_cast<short*>(&hb);
                    }
                    *(short4v*)(hs + p * KS + m0) = pk;
                }
            }
        __syncthreads();  // hs complete

        // ---- GEMM2 (16x16x32, r5-proven): out16 = W2 @ h ----
        float4v acc2[2];
        acc2[0] = (float4v)0.0f;
        acc2[1] = (float4v)0.0f;
#pragma unroll
        for (int r = 0; r < 4; ++r) {
#pragma unroll
            for (int i = 0; i < 2; ++i) {
                int p = (wave * 2 + i) * 16 + hl;
                short8 bfrag = *(const short8*)(hs + p * KS + r * 32 + quad * 8);
                acc2[i] = __builtin_amdgcn_mfma_f32_16x16x32_bf16(
                    w2frag[r], bfrag, acc2[i], 0, 0, 0);
            }
        }

        // ---- store out[b][w0+nt][h0+hl][r0..r0+3] fp32, coalesced ----
#pragma unroll
        for (int i = 0; i < 2; ++i) {
            int nt = wave * 2 + i;
            size_t ofs = (((size_t)b * 128 + (w0 + nt)) * 128 + (h0 + hl)) * 16 + r0;
            float4 v = make_float4(acc2[i][0] + b2r[0], acc2[i][1] + b2r[1],
                                   acc2[i][2] + b2r[2], acc2[i][3] + b2r[3]);
            *(float4*)(out + ofs) = v;
        }
        buf ^= 1;
    }
#undef LOAD_TILE
}

// ---------------- fallback (round-3 proven kernel, fp32 x, 128-px tiles) ----------------
__global__ __launch_bounds__(256, 2) void nca_mfma_fb(const float* __restrict__ x,
                                                      const bf16* __restrict__ wsb,
                                                      const float* __restrict__ wsf,
                                                      float* __restrict__ out,
                                                      int gridTiles) {
    __shared__ bf16 xsb[HALO_W * HALO_H * CS];
    __shared__ bf16 hsb[128 * KS];

    const int tid = threadIdx.x;
    const int wave = tid >> 6;
    const int lane = tid & 63;
    const int hl = lane & 15;
    const int quad = lane >> 4;
    const int r0 = quad * 4;
    const int mgrp = wave >> 1;
    const int ngrp = wave & 1;

    short8 afrag[4][5];
#pragma unroll
    for (int mt = 0; mt < 4; ++mt) {
        int m = mgrp * 64 + mt * 16 + hl;
#pragma unroll
        for (int q = 0; q < 5; ++q)
            afrag[mt][q] = *(const short8*)(wsb + m * 160 + q * 32 + quad * 8);
    }
    short8 w2frag[4];
#pragma unroll
    for (int r = 0; r < 4; ++r)
        w2frag[r] = *(const short8*)(wsb + W2B_EL + hl * 128 + r * 32 + quad * 8);
    float b1r[4][4];
#pragma unroll
    for (int mt = 0; mt < 4; ++mt)
#pragma unroll
        for (int r = 0; r < 4; ++r) b1r[mt][r] = wsf[mgrp * 64 + mt * 16 + r0 + r];
    float b2r[4];
#pragma unroll
    for (int r = 0; r < 4; ++r) b2r[r] = wsf[128 + r0 + r];

    for (int t = blockIdx.x; t < 4096; t += gridTiles) {
        int b = t >> 7;
        int rem = t & 127;
        int wt = rem >> 3, ht = rem & 7;
        int h0 = ht * 16, w0 = wt * 8;

        __syncthreads();

        const float* xb = x + (size_t)b * 16 * 128 * 128;
        for (int f = tid; f < 16 * HALO_H * HALO_W; f += 256) {
            int c = f / (HALO_H * HALO_W);
            int rr = f - c * (HALO_H * HALO_W);
            int hh = rr / HALO_W;
            int ww = rr - hh * HALO_W;
            int gh = h0 - 1 + hh, gw = w0 - 1 + ww;
            float v = 0.0f;
            if ((unsigned)gh < 128u && (unsigned)gw < 128u)
                v = xb[(c * 128 + gh) * 128 + gw];
            xsb[(ww * HALO_H + hh) * CS + c] = __float2bfloat16(v);
        }
        __syncthreads();

        float4v acc[4][4];
#pragma unroll
        for (int mt = 0; mt < 4; ++mt)
#pragma unroll
            for (int nt = 0; nt < 4; ++nt) acc[mt][nt] = (float4v)0.0f;

#pragma unroll
        for (int q = 0; q < 5; ++q) {
            int g = q * 2 + (quad >> 1);
            if (g > 8) g = 8;
            int kh = g / 3, kw = g - kh * 3;
            int c0 = (quad & 1) * 8;
            short8 bfrag[4];
#pragma unroll
            for (int nt = 0; nt < 4; ++nt) {
                int ww = ngrp * 4 + nt + kw;
                bfrag[nt] = *(const short8*)(xsb + (ww * HALO_H + hl + kh) * CS + c0);
            }
#pragma unroll
            for (int nt = 0; nt < 4; ++nt)
#pragma unroll
                for (int mt = 0; mt < 4; ++mt)
                    acc[mt][nt] = __builtin_amdgcn_mfma_f32_16x16x32_bf16(
                        afrag[mt][q], bfrag[nt], acc[mt][nt], 0, 0, 0);
        }

#pragma unroll
        for (int mt = 0; mt < 4; ++mt)
#pragma unroll
            for (int nt = 0; nt < 4; ++nt) {
                int p = (ngrp * 4 + nt) * 16 + hl;
                int m = mgrp * 64 + mt * 16 + r0;
                short4v pk;
#pragma unroll
                for (int r = 0; r < 4; ++r) {
                    float v = acc[mt][nt][r] + b1r[mt][r];
                    v = fmaxf(v, 0.0f);
                    bf16 hb = __float2bfloat16(v);
                    pk[r] = *reinterpret_cast<short*>(&hb);
                }
                *(short4v*)(hsb + p * KS + m) = pk;
            }
        __syncthreads();

        float4v acc2[2];
        acc2[0] = (float4v)0.0f;
        acc2[1] = (float4v)0.0f;
#pragma unroll
        for (int r = 0; r < 4; ++r) {
#pragma unroll
            for (int i = 0; i < 2; ++i) {
                int p = (wave * 2 + i) * 16 + hl;
                short8 bfrag = *(const short8*)(hsb + p * KS + r * 32 + quad * 8);
                acc2[i] = __builtin_amdgcn_mfma_f32_16x16x32_bf16(
                    w2frag[r], bfrag, acc2[i], 0, 0, 0);
            }
        }

#pragma unroll
        for (int i = 0; i < 2; ++i) {
            int nt = wave * 2 + i;
            size_t ofs = (((size_t)b * 128 + (w0 + nt)) * 128 + (h0 + hl)) * 16 + r0;
            float4 v = make_float4(acc2[i][0] + b2r[0], acc2[i][1] + b2r[1],
                                   acc2[i][2] + b2r[2], acc2[i][3] + b2r[3]);
            *(float4*)(out + ofs) = v;
        }
    }
}

extern "C" void kernel_launch(void* const* d_in, const int* in_sizes, int n_in,
                              void* d_out, int out_size, void* d_ws, size_t ws_size,
                              hipStream_t stream) {
    const float* x  = (const float*)d_in[0];
    const float* Wx = (const float*)d_in[1];
    const float* bx = (const float*)d_in[2];
    const float* Wy = (const float*)d_in[3];
    const float* by = (const float*)d_in[4];
    const float* W1 = (const float*)d_in[5];
    const float* b1 = (const float*)d_in[6];
    const float* W2 = (const float*)d_in[7];
    const float* b2 = (const float*)d_in[8];
    bf16* wsb = (bf16*)d_ws;
    float* wsf = (float*)((char*)d_ws + WSF_BYTE);
    bf16* xT = (bf16*)((char*)d_ws + XT_BYTE);
    float* out = (float*)d_out;

    const size_t need = (size_t)XT_BYTE + (size_t)32 * 128 * 128 * 16 * 2;  // 16.8 MB
    const bool big = ws_size >= need;
    const int tb = big ? 4096 : 0;

    hipLaunchKernelGGL(prep_all, dim3(tb + 80), dim3(256), 0, stream,
                       x, Wx, bx, Wy, by, W1, b1, W2, b2, wsb, wsf, xT, tb);
    if (big) {
        const int grid = 512;  // 2 blocks/CU, 8 tiles/block, zero tail
        hipLaunchKernelGGL(nca_mfma_w, dim3(grid), dim3(256), 0, stream,
                           xT, wsb, wsf, out, grid);
    } else {
        const int grid = 1024;
        hipLaunchKernelGGL(nca_mfma_fb, dim3(grid), dim3(256), 0, stream,
                           x, wsb, wsf, out, grid);
    }
}